// Round 4
// baseline (440.616 us; speedup 1.0000x reference)
//
#include <hip/hip_runtime.h>
#include <math.h>

#define HH 16
#define SS 2048
#define DD 128
#define NROWS (HH * SS)            // 32768
#define OUTSZ (HH * SS * DD)       // 4194304 elems per tensor

typedef __attribute__((ext_vector_type(8))) short bf16x8;
typedef __attribute__((ext_vector_type(4))) float f32x4;
typedef __attribute__((ext_vector_type(8))) unsigned short u16x8;

#define MFMA16(a, b, c) __builtin_amdgcn_mfma_f32_16x16x32_bf16(a, b, c, 0, 0, 0)

__device__ __forceinline__ unsigned short f2bf(float f) {
    unsigned u = __float_as_uint(f);
    return (unsigned short)((u + 0x7FFFu + ((u >> 16) & 1u)) >> 16);   // RNE
}
__device__ __forceinline__ bf16x8 negf(bf16x8 a) {
    bf16x8 r;
#pragma unroll
    for (int j = 0; j < 8; ++j) r[j] = (short)(a[j] ^ (short)0x8000);
    return r;
}

struct ClinPtrs {
    const float* xr; const float* xi;
    const float* gr; const float* gi;     // GATE only
    const float* wr; const float* wi;
    const float* br; const float* bi;
    const float* per; const float* pei;   // may be null
    void* yr; void* yi;
    int outbf;                            // 1: bf16 out, 0: fp32 out
};

// ---------------------------------------------------------------------------
// MFMA complex linear. 512 thr = 8 waves, 128 rows/block, full 128 cols.
// grid (NROWS/128, nproj). W (both comps) staged bf16 in LDS once per block.
// GATE: x = (xr,xi) (*) (gr,gi) complex product at fragment build.
// In-place final proj is safe: each wave reads its 16-row slab into frags
// before its own epilogue stores; slabs are wave-disjoint.
// ---------------------------------------------------------------------------
template <bool GATE>
__global__ __launch_bounds__(512, 2)
void clin_mfma(ClinPtrs P0, ClinPtrs P1, ClinPtrs P2, ClinPtrs P3) {
    __shared__ unsigned short wsh[2][DD][136];   // 69632 B

    const int py = blockIdx.y;
    const ClinPtrs P = (py == 0) ? P0 : (py == 1) ? P1 : (py == 2) ? P2 : P3;

    const int t = threadIdx.x;
    // ---- stage W fp32->bf16 (4096 groups of 8) ----
#pragma unroll
    for (int u = 0; u < 8; ++u) {
        const int f = t + 512 * u;
        const int c = f >> 11;
        const int rem = f & 2047;
        const int row = rem >> 4;
        const int g8 = (rem & 15) * 8;
        const float* src = (c ? P.wi : P.wr) + (long)row * DD + g8;
        const float4 a = *(const float4*)src;
        const float4 b = *(const float4*)(src + 4);
        unsigned short tmp[8] = {f2bf(a.x), f2bf(a.y), f2bf(a.z), f2bf(a.w),
                                 f2bf(b.x), f2bf(b.y), f2bf(b.z), f2bf(b.w)};
        *(u16x8*)&wsh[c][row][g8] = *(u16x8*)tmp;
    }

    const int w = t >> 6, lane = t & 63;
    const int lm = lane & 15, quad = lane >> 4;
    const long m0 = (long)blockIdx.x * 128 + w * 16;

    // ---- A fragments: rows m0+lm, k = dk*32 + quad*8 + j ----
    bf16x8 xrf[4], xif[4];
    {
        const long rbase = (m0 + lm) * DD;
#pragma unroll
        for (int dk = 0; dk < 4; ++dk) {
            const long o = rbase + dk * 32 + quad * 8;
            const float4 a0 = *(const float4*)(P.xr + o);
            const float4 a1 = *(const float4*)(P.xr + o + 4);
            const float4 b0 = *(const float4*)(P.xi + o);
            const float4 b1 = *(const float4*)(P.xi + o + 4);
            float fr[8] = {a0.x, a0.y, a0.z, a0.w, a1.x, a1.y, a1.z, a1.w};
            float fi[8] = {b0.x, b0.y, b0.z, b0.w, b1.x, b1.y, b1.z, b1.w};
            if (GATE) {
                const float4 c0v = *(const float4*)(P.gr + o);
                const float4 c1v = *(const float4*)(P.gr + o + 4);
                const float4 d0v = *(const float4*)(P.gi + o);
                const float4 d1v = *(const float4*)(P.gi + o + 4);
                const float ur[8] = {c0v.x, c0v.y, c0v.z, c0v.w, c1v.x, c1v.y, c1v.z, c1v.w};
                const float ui[8] = {d0v.x, d0v.y, d0v.z, d0v.w, d1v.x, d1v.y, d1v.z, d1v.w};
#pragma unroll
                for (int j = 0; j < 8; ++j) {
                    const float pr = fr[j] * ur[j] - fi[j] * ui[j];
                    const float pi = fr[j] * ui[j] + fi[j] * ur[j];
                    fr[j] = pr; fi[j] = pi;
                }
            }
#pragma unroll
            for (int j = 0; j < 8; ++j) {
                xrf[dk][j] = (short)f2bf(fr[j]);
                xif[dk][j] = (short)f2bf(fi[j]);
            }
        }
    }

    f32x4 Or[8], Oi[8];
    const f32x4 z = {0.f, 0.f, 0.f, 0.f};
#pragma unroll
    for (int nt = 0; nt < 8; ++nt) { Or[nt] = z; Oi[nt] = z; }

    __syncthreads();

#pragma unroll
    for (int dk = 0; dk < 4; ++dk) {
        const bf16x8 nxi = negf(xif[dk]);
        const int off = dk * 32 + quad * 8;
#pragma unroll
        for (int nt = 0; nt < 8; ++nt) {
            const bf16x8 wrf = *(bf16x8*)&wsh[0][nt * 16 + lm][off];
            const bf16x8 wif = *(bf16x8*)&wsh[1][nt * 16 + lm][off];
            Or[nt] = MFMA16(xrf[dk], wrf, Or[nt]);
            Or[nt] = MFMA16(nxi,     wif, Or[nt]);
            Oi[nt] = MFMA16(xrf[dk], wif, Oi[nt]);
            Oi[nt] = MFMA16(xif[dk], wrf, Oi[nt]);
        }
    }

    // ---- epilogue: C layout row = quad*4+reg, col = nt*16 + lm ----
#pragma unroll
    for (int nt = 0; nt < 8; ++nt) {
        const int c = nt * 16 + lm;
        const float bra = P.br[c], bia = P.bi[c];
#pragma unroll
        for (int reg = 0; reg < 4; ++reg) {
            const long R = m0 + quad * 4 + reg;
            float vr = Or[nt][reg] + bra;
            float vi = Oi[nt][reg] + bia;
            if (P.per != nullptr) {
                vr += P.per[R * DD + c];
                vi += P.pei[R * DD + c];
            }
            if (P.outbf) {
                ((unsigned short*)P.yr)[R * DD + c] = f2bf(vr);
                ((unsigned short*)P.yi)[R * DD + c] = f2bf(vi);
            } else {
                ((float*)P.yr)[R * DD + c] = vr;
                ((float*)P.yi)[R * DD + c] = vi;
            }
        }
    }
}

// ---------------------------------------------------------------------------
// MFMA flash attention, complex-magnitude scores. bf16 q,k,v inputs.
// R4: 256 thr = 4 waves, each wave owns 32 q-rows (2 slabs of 16), Bq=128,
// Bk=32, grid 256 XCD-swizzled. Rationale (R3 counters): kernel is
// LDS-pipe-bound (264 ds_read_b128/CU/k-tile ~ 3170cy + conflicts ~ whole
// dur). K/V fragment reads per wave are independent of rows/wave, so
// 32 rows/wave halves per-CU LDS reads for the same work. 1 wave/SIMD is
// acceptable: the binding resource is the per-CU LDS pipe, not TLP; and
// it unlocks the full 512-reg budget (launch_bounds(256,1)) so acc(128)
// + Q/negQ frags(96) + staging regs fit spill-free.
// Keeps: double-buffered K/V + register prefetch (issue-early),
// fixed-offset softmax (no max tracking; magnitude scores bounded).
// ---------------------------------------------------------------------------
__global__ __launch_bounds__(256, 1)
void attn_mfma(const unsigned short* __restrict__ qr, const unsigned short* __restrict__ qi,
               const unsigned short* __restrict__ kr, const unsigned short* __restrict__ ki,
               const unsigned short* __restrict__ vr, const unsigned short* __restrict__ vi,
               float* __restrict__ out_r, float* __restrict__ out_i) {
    __shared__ unsigned short ks[2][2][32][136];   // 34816 B  [buf][comp][k][d]
    __shared__ unsigned short vt[2][2][DD][40];    // 40960 B  [buf][comp][d][k]
    __shared__ unsigned short ps[128][40];         // 10240 B  (P, bf16)

    const int t = threadIdx.x;
    const int w = t >> 6, lane = t & 63;
    const int lm = lane & 15, quad = lane >> 4;

    // XCD swizzle: xcd = bid%8; head h = xcd + 8*(rr>>4); qt = rr&15
    const int bid = blockIdx.x;
    const int xcd = bid & 7;
    const int rr = bid >> 3;          // 0..31
    const int qt = rr & 15;
    const int h  = xcd + 8 * (rr >> 4);
    const long hbase = (long)h * SS * DD;
    const int q0 = qt * 128;
    const float scale = 0.08838834764831845f;   // 128^-0.5

    // ---- staging thread->element maps (constant per thread, 256 thr) ----
    // K: 32 rows x 16 groups x 2 comps = 1024 u16x8 slots, 4 per thread
    int kC[4], kR[4], kG[4];
    const unsigned short* kp[4];
#pragma unroll
    for (int u = 0; u < 4; ++u) {
        const int f = t + 256 * u;
        kC[u] = f >> 9;                 // 0: kr, 1: ki
        kR[u] = (f & 511) >> 4;         // k row 0..31
        kG[u] = (f & 15) * 8;           // d group
        kp[u] = (kC[u] ? ki : kr) + hbase + (long)kR[u] * DD + kG[u];
    }
    // V: 2 comps x 16 d-groups x 16 k-pairs = 512 slots, 2 per thread
    int vC[2], vS2[2], vD8[2];
    const unsigned short* vp[2];
#pragma unroll
    for (int u = 0; u < 2; ++u) {
        const int f = t + 256 * u;
        vC[u] = f >> 8;                 // 0: vr, 1: vi
        vS2[u] = (f & 15) * 2;          // k pair 0..30
        vD8[u] = ((f >> 4) & 15) * 8;   // d group
        vp[u] = (vC[u] ? vi : vr) + hbase + (long)vS2[u] * DD + vD8[u];
    }

    u16x8 kA[4], vA0[2], vA1[2];        // in-flight staging registers
    // ---- issue tile-0 loads ----
#pragma unroll
    for (int u = 0; u < 4; ++u) kA[u] = *(const u16x8*)(kp[u]);
#pragma unroll
    for (int u = 0; u < 2; ++u) {
        vA0[u] = *(const u16x8*)(vp[u]);
        vA1[u] = *(const u16x8*)(vp[u] + DD);
    }

    // ---- resident Q fragments (A layout), 2 slabs of 16 rows per wave ----
    bf16x8 qrf[2][4], qif[2][4], nqrf[2][4];
#pragma unroll
    for (int s = 0; s < 2; ++s) {
        const long rb = hbase + (long)(q0 + w * 32 + s * 16 + lm) * DD;
#pragma unroll
        for (int dk = 0; dk < 4; ++dk) {
            qrf[s][dk] = *(const bf16x8*)(qr + rb + dk * 32 + quad * 8);
            qif[s][dk] = *(const bf16x8*)(qi + rb + dk * 32 + quad * 8);
            nqrf[s][dk] = negf(qrf[s][dk]);
        }
    }

    f32x4 Or[2][8], Oi[2][8];
    const f32x4 z = {0.f, 0.f, 0.f, 0.f};
#pragma unroll
    for (int s = 0; s < 2; ++s)
#pragma unroll
        for (int nt = 0; nt < 8; ++nt) { Or[s][nt] = z; Oi[s][nt] = z; }
    float l_st[2][4] = {{0.f, 0.f, 0.f, 0.f}, {0.f, 0.f, 0.f, 0.f}};

    // ---- write tile 0 into buf 0 ----
#pragma unroll
    for (int u = 0; u < 4; ++u)
        *(u16x8*)&ks[0][kC[u]][kR[u]][kG[u]] = kA[u];
#pragma unroll
    for (int u = 0; u < 2; ++u)
#pragma unroll
        for (int j = 0; j < 8; ++j) {
            const unsigned val = (unsigned)(unsigned short)vA0[u][j] |
                                 ((unsigned)(unsigned short)vA1[u][j] << 16);
            *(unsigned*)&vt[0][vC[u]][vD8[u] + j][vS2[u]] = val;
        }
    __syncthreads();

    for (int kt = 0; kt < SS / 32; ++kt) {
        const int b = kt & 1;
        // ---- issue next tile's global loads (latency hides under compute) ----
        if (kt + 1 < SS / 32) {
            const long koff = (long)(kt + 1) * 32 * DD;
#pragma unroll
            for (int u = 0; u < 4; ++u) kA[u] = *(const u16x8*)(kp[u] + koff);
#pragma unroll
            for (int u = 0; u < 2; ++u) {
                vA0[u] = *(const u16x8*)(vp[u] + koff);
                vA1[u] = *(const u16x8*)(vp[u] + koff + DD);
            }
        }

        // ---- scores: K frags loaded once per dk, feed BOTH slabs ----
        f32x4 sr0[2] = {z, z}, sr1[2] = {z, z}, si0[2] = {z, z}, si1[2] = {z, z};
#pragma unroll
        for (int dk = 0; dk < 4; ++dk) {
            const int off = dk * 32 + quad * 8;
            const bf16x8 kf0 = *(bf16x8*)&ks[b][0][lm][off];
            const bf16x8 kg0 = *(bf16x8*)&ks[b][1][lm][off];
            const bf16x8 kf1 = *(bf16x8*)&ks[b][0][16 + lm][off];
            const bf16x8 kg1 = *(bf16x8*)&ks[b][1][16 + lm][off];
#pragma unroll
            for (int s = 0; s < 2; ++s) {
                sr0[s] = MFMA16(qrf[s][dk], kf0, sr0[s]);  sr0[s] = MFMA16(qif[s][dk], kg0, sr0[s]);
                si0[s] = MFMA16(qif[s][dk], kf0, si0[s]);  si0[s] = MFMA16(nqrf[s][dk], kg0, si0[s]);
                sr1[s] = MFMA16(qrf[s][dk], kf1, sr1[s]);  sr1[s] = MFMA16(qif[s][dk], kg1, sr1[s]);
                si1[s] = MFMA16(qif[s][dk], kf1, si1[s]);  si1[s] = MFMA16(nqrf[s][dk], kg1, si1[s]);
            }
        }

        // ---- fixed-offset softmax: p = exp(s), no max tracking ----
#pragma unroll
        for (int s = 0; s < 2; ++s)
#pragma unroll
            for (int reg = 0; reg < 4; ++reg) {
                const float s0 = __builtin_amdgcn_sqrtf(
                    fmaf(sr0[s][reg], sr0[s][reg], fmaf(si0[s][reg], si0[s][reg], 1e-8f))) * scale;
                const float s1 = __builtin_amdgcn_sqrtf(
                    fmaf(sr1[s][reg], sr1[s][reg], fmaf(si1[s][reg], si1[s][reg], 1e-8f))) * scale;
                const float p0 = __expf(s0);
                const float p1 = __expf(s1);
                l_st[s][reg] += p0 + p1;
                ps[w * 32 + s * 16 + quad * 4 + reg][lm]      = f2bf(p0);
                ps[w * 32 + s * 16 + quad * 4 + reg][16 + lm] = f2bf(p1);
            }

        // ---- PV: V frags loaded once per nt, feed BOTH slabs ----
        bf16x8 pf[2];
#pragma unroll
        for (int s = 0; s < 2; ++s)
            pf[s] = *(bf16x8*)&ps[w * 32 + s * 16 + lm][quad * 8];
#pragma unroll
        for (int nt = 0; nt < 8; ++nt) {
            const bf16x8 vrf = *(bf16x8*)&vt[b][0][nt * 16 + lm][quad * 8];
            const bf16x8 vif = *(bf16x8*)&vt[b][1][nt * 16 + lm][quad * 8];
#pragma unroll
            for (int s = 0; s < 2; ++s) {
                Or[s][nt] = MFMA16(pf[s], vrf, Or[s][nt]);
                Oi[s][nt] = MFMA16(pf[s], vif, Oi[s][nt]);
            }
        }

        // ---- write prefetched tile into other buffer ----
        if (kt + 1 < SS / 32) {
            __syncthreads();   // all waves done reading buf b^1 (iter kt-1)
#pragma unroll
            for (int u = 0; u < 4; ++u)
                *(u16x8*)&ks[b ^ 1][kC[u]][kR[u]][kG[u]] = kA[u];
#pragma unroll
            for (int u = 0; u < 2; ++u)
#pragma unroll
                for (int j = 0; j < 8; ++j) {
                    const unsigned val = (unsigned)(unsigned short)vA0[u][j] |
                                         ((unsigned)(unsigned short)vA1[u][j] << 16);
                    *(unsigned*)&vt[b ^ 1][vC[u]][vD8[u] + j][vS2[u]] = val;
                }
            __syncthreads();   // writes visible before iter kt+1 reads
        }
    }

    // ---- finalize: reduce l across 16-lane group, scale, store ----
#pragma unroll
    for (int s = 0; s < 2; ++s) {
        float linv[4];
#pragma unroll
        for (int reg = 0; reg < 4; ++reg) {
            float l = l_st[s][reg];
#pragma unroll
            for (int off = 1; off < 16; off <<= 1) l += __shfl_xor(l, off);
            linv[reg] = 1.f / l;
        }
        const long ob = hbase + (long)(q0 + w * 32 + s * 16) * DD;
#pragma unroll
        for (int nt = 0; nt < 8; ++nt) {
            const int c = nt * 16 + lm;
#pragma unroll
            for (int reg = 0; reg < 4; ++reg) {
                const long R = ob + (long)(quad * 4 + reg) * DD + c;
                out_r[R] = Or[s][nt][reg] * linv[reg];
                out_i[R] = Oi[s][nt][reg] * linv[reg];
            }
        }
    }
}

// ---------------------------------------------------------------------------
extern "C" void kernel_launch(void* const* d_in, const int* in_sizes, int n_in,
                              void* d_out, int out_size, void* d_ws, size_t ws_size,
                              hipStream_t stream) {
    const float* q_r    = (const float*)d_in[0];
    const float* q_i    = (const float*)d_in[1];
    const float* k_r    = (const float*)d_in[2];
    const float* k_i    = (const float*)d_in[3];
    const float* v_r    = (const float*)d_in[4];
    const float* v_i    = (const float*)d_in[5];
    const float* pe_q_r = (const float*)d_in[6];
    const float* pe_q_i = (const float*)d_in[7];
    const float* pe_k_r = (const float*)d_in[8];
    const float* pe_k_i = (const float*)d_in[9];
    const float* qw_r = (const float*)d_in[10];
    const float* qw_i = (const float*)d_in[11];
    const float* qb_r = (const float*)d_in[12];
    const float* qb_i = (const float*)d_in[13];
    const float* kw_r = (const float*)d_in[14];
    const float* kw_i = (const float*)d_in[15];
    const float* kb_r = (const float*)d_in[16];
    const float* kb_i = (const float*)d_in[17];
    const float* vw_r = (const float*)d_in[18];
    const float* vw_i = (const float*)d_in[19];
    const float* vb_r = (const float*)d_in[20];
    const float* vb_i = (const float*)d_in[21];
    const float* gw_r = (const float*)d_in[22];
    const float* gw_i = (const float*)d_in[23];
    const float* gb_r = (const float*)d_in[24];
    const float* gb_i = (const float*)d_in[25];
    const float* ow_r = (const float*)d_in[26];
    const float* ow_i = (const float*)d_in[27];
    const float* ob_r = (const float*)d_in[28];
    const float* ob_i = (const float*)d_in[29];

    float* out_r = (float*)d_out;              // attn a_r temp, then final out_r
    float* out_i = out_r + (long)OUTSZ;
    float* g_r   = out_r + 2L * OUTSZ;
    float* g_i   = out_r + 3L * OUTSZ;

    unsigned short* ws = (unsigned short*)d_ws; // 6 x 8 MiB bf16
    unsigned short* pqr = ws + 0L * OUTSZ;
    unsigned short* pqi = ws + 1L * OUTSZ;
    unsigned short* pkr = ws + 2L * OUTSZ;
    unsigned short* pki = ws + 3L * OUTSZ;
    unsigned short* pvr = ws + 4L * OUTSZ;
    unsigned short* pvi = ws + 5L * OUTSZ;

    const dim3 blk(512);

    ClinPtrs P0 = {q_r, q_i, nullptr, nullptr, qw_r, qw_i, qb_r, qb_i,
                   pe_q_r, pe_q_i, pqr, pqi, 1};
    ClinPtrs P1 = {k_r, k_i, nullptr, nullptr, kw_r, kw_i, kb_r, kb_i,
                   pe_k_r, pe_k_i, pkr, pki, 1};
    ClinPtrs P2 = {v_r, v_i, nullptr, nullptr, vw_r, vw_i, vb_r, vb_i,
                   nullptr, nullptr, pvr, pvi, 1};
    ClinPtrs P3 = {q_r, q_i, nullptr, nullptr, gw_r, gw_i, gb_r, gb_i,
                   nullptr, nullptr, g_r, g_i, 0};

    // all 4 projections in one launch: grid (256 row-blocks, 4 projections)
    clin_mfma<false><<<dim3(NROWS / 128, 4), blk, 0, stream>>>(P0, P1, P2, P3);

    // flash attention -> a_r, a_i parked in d_out slots 0,1
    attn_mfma<<<dim3((SS / 128) * HH), dim3(256), 0, stream>>>(
        pqr, pqi, pkr, pki, pvr, pvi, out_r, out_i);

    // gate + o-projection, in-place over d_out slots 0,1 (wave-disjoint rows)
    ClinPtrs PF = {g_r, g_i, out_r, out_i, ow_r, ow_i, ob_r, ob_i,
                   nullptr, nullptr, out_r, out_i, 0};
    clin_mfma<true><<<dim3(NROWS / 128, 1), blk, 0, stream>>>(PF, PF, PF, PF);
}